// Round 1
// baseline (792.967 us; speedup 1.0000x reference)
//
#include <hip/hip_runtime.h>
#include <stdint.h>

#define T_SEQ 2048
#define HIDDEN 4096
#define NUM_HEADS 32
#define NUM_KV 8
#define HD 128
#define QSIZE (NUM_HEADS * HD)       /* 4096 */
#define KVSIZE (NUM_KV * HD)         /* 1024 */
#define QKV_N (QSIZE + 2 * KVSIZE)   /* 6144 */

typedef __attribute__((ext_vector_type(8))) __bf16 bf16x8;
typedef __attribute__((ext_vector_type(4))) float f32x4;

// ---------- helpers ----------
static __device__ __forceinline__ unsigned short f2bf(float f) {
  union { float f; unsigned int u; } v; v.f = f;
  unsigned int u = v.u;
  return (unsigned short)((u + 0x7FFFu + ((u >> 16) & 1u)) >> 16);
}

static __device__ __forceinline__ void async16(const void* g, void* l) {
  __builtin_amdgcn_global_load_lds((__attribute__((address_space(1))) void*)g,
                                   (__attribute__((address_space(3))) void*)l,
                                   16, 0, 0);
}

static __device__ __forceinline__ bf16x8 lds_frag(const unsigned short* p) {
  return *(const bf16x8*)p;
}

// ---------- fp32 -> bf16 cast ----------
__global__ void cvt_f32_bf16(const float* __restrict__ src,
                             unsigned short* __restrict__ dst, int n4) {
  int i = blockIdx.x * 256 + threadIdx.x;
  if (i >= n4) return;
  float4 f = ((const float4*)src)[i];
  ushort4 o;
  o.x = f2bf(f.x); o.y = f2bf(f.y); o.z = f2bf(f.z); o.w = f2bf(f.w);
  ((ushort4*)dst)[i] = o;
}

// ---------- GEMM: C[M][N] = A[M][K] * Bt[N][K]^T (+bias) ----------
// m97-verified structure: 128x128 tile, BK=32, 4 waves (2x2), 4x4 16x16x32 MFMA per wave.
__global__ __launch_bounds__(256) void gemm_bt(
    const unsigned short* __restrict__ A,
    const unsigned short* __restrict__ Bt,
    const float* __restrict__ bias,
    float* __restrict__ C, int M, int N, int K) {
  __shared__ unsigned short lds_a[128 * 32];
  __shared__ unsigned short lds_b[128 * 32];
  const int tid = threadIdx.x;
  const int wave = tid >> 6, lane = tid & 63;
  const int quad = lane >> 4, l16 = lane & 15;
  const int row0 = blockIdx.x * 128, col0 = blockIdx.y * 128;
  const int wm = (wave >> 1) * 64, wn = (wave & 1) * 64;

  f32x4 acc[4][4] = {};

  // staging: wave w, issue it: flat elems e = (w*2+it)*512 + lane*8 (row = e/32, k = e%32)
  const int e0 = wave * 1024 + lane * 8;
  const int e1 = e0 + 512;
  const unsigned short* Ab0 = A + (size_t)(row0 + (e0 >> 5)) * K + (e0 & 31);
  const unsigned short* Ab1 = A + (size_t)(row0 + (e1 >> 5)) * K + (e1 & 31);
  const unsigned short* Bb0 = Bt + (size_t)(col0 + (e0 >> 5)) * K + (e0 & 31);
  const unsigned short* Bb1 = Bt + (size_t)(col0 + (e1 >> 5)) * K + (e1 & 31);
  unsigned short* la0 = lds_a + wave * 1024;
  unsigned short* la1 = la0 + 512;
  unsigned short* lb0 = lds_b + wave * 1024;
  unsigned short* lb1 = lb0 + 512;

  for (int k0 = 0; k0 < K; k0 += 32) {
    __syncthreads();
    async16(Ab0 + k0, la0);
    async16(Ab1 + k0, la1);
    async16(Bb0 + k0, lb0);
    async16(Bb1 + k0, lb1);
    __syncthreads();
    bf16x8 af[4], bfr[4];
#pragma unroll
    for (int mt = 0; mt < 4; mt++)
      af[mt] = lds_frag(lds_a + (wm + mt * 16 + l16) * 32 + quad * 8);
#pragma unroll
    for (int nt = 0; nt < 4; nt++)
      bfr[nt] = lds_frag(lds_b + (wn + nt * 16 + l16) * 32 + quad * 8);
#pragma unroll
    for (int mt = 0; mt < 4; mt++)
#pragma unroll
      for (int nt = 0; nt < 4; nt++)
        acc[mt][nt] = __builtin_amdgcn_mfma_f32_16x16x32_bf16(
            af[mt], bfr[nt], acc[mt][nt], 0, 0, 0);
  }

#pragma unroll
  for (int mt = 0; mt < 4; mt++) {
#pragma unroll
    for (int nt = 0; nt < 4; nt++) {
      const int c = col0 + wn + nt * 16 + l16;
      const float bv = bias ? bias[c] : 0.0f;
      const int rbase = row0 + wm + mt * 16 + quad * 4;
#pragma unroll
      for (int r = 0; r < 4; r++)
        C[(size_t)(rbase + r) * N + c] = acc[mt][nt][r] + bv;
    }
  }
}

// ---------- RMSNorm + RoPE, emit head-major bf16 q/k/v ----------
// grid (48, 2048), block 128. slot 0..31 = q head, 32..39 = k head, 40..47 = v head.
__global__ void norm_rope(const float* __restrict__ qkv,
                          const float* __restrict__ qw,
                          const float* __restrict__ kw,
                          unsigned short* __restrict__ q,
                          unsigned short* __restrict__ k,
                          unsigned short* __restrict__ v) {
  const int slot = blockIdx.x;
  const int t = blockIdx.y;
  const int d = threadIdx.x;
  const float* src;
  if (slot < 32)      src = qkv + (size_t)t * QKV_N + slot * HD;
  else if (slot < 40) src = qkv + (size_t)t * QKV_N + QSIZE + (slot - 32) * HD;
  else                src = qkv + (size_t)t * QKV_N + QSIZE + KVSIZE + (slot - 40) * HD;
  float x = src[d];
  if (slot >= 40) {  // v: plain cast (uniform branch per block)
    v[((size_t)(slot - 40) * T_SEQ + t) * HD + d] = f2bf(x);
    return;
  }
  __shared__ float red[2];
  __shared__ float ylds[HD];
  float ss = x * x;
#pragma unroll
  for (int m = 32; m >= 1; m >>= 1) ss += __shfl_xor(ss, m, 64);
  if ((d & 63) == 0) red[d >> 6] = ss;
  __syncthreads();
  const float rn = rsqrtf((red[0] + red[1]) * (1.0f / 128.0f) + 1e-5f);
  const float* w = (slot < 32) ? qw : kw;
  const float y = x * rn * w[d];
  ylds[d] = y;
  __syncthreads();
  float out;
  if (d < 64) {
    const int j = d & 31;
    // inv_freq[j] = 10000^(-j/32); positions == arange(T) so pos = t
    const float inv = exp2f(-(float)j * (13.28771237954945f / 32.0f));
    const float ang = (float)t * inv;
    float s, c;
    sincosf(ang, &s, &c);
    const float x1 = ylds[j], x2 = ylds[j + 32];
    out = (d < 32) ? (x1 * c - x2 * s) : (x2 * c + x1 * s);
  } else {
    out = y;
  }
  if (slot < 32) q[((size_t)slot * T_SEQ + t) * HD + d] = f2bf(out);
  else           k[((size_t)(slot - 32) * T_SEQ + t) * HD + d] = f2bf(out);
}

// ---------- flash attention (causal, GQA 4:1) ----------
// grid (32 heads, 32 q-blocks), 256 threads. Wave w owns q-rows [q0+16w, q0+16w+16).
#define PK 136  /* 128+8: padded K-tile row stride (elems) */
#define PV 40   /* 32+8:  padded Vt / P row stride (elems) */
__global__ __launch_bounds__(256) void attn_fwd(
    const unsigned short* __restrict__ Q,  // [32][2048][128]
    const unsigned short* __restrict__ K,  // [8][2048][128]
    const unsigned short* __restrict__ V,  // [8][2048][128]
    unsigned short* __restrict__ O) {      // [2048][4096]
  __shared__ unsigned short lds_k[32 * PK];
  __shared__ unsigned short lds_vt[128 * PV];
  __shared__ unsigned short lds_p[4][16 * PV];

  const int h = blockIdx.x, qb = blockIdx.y;
  const int kvh = h >> 2;
  const int tid = threadIdx.x, wave = tid >> 6, lane = tid & 63;
  const int quad = lane >> 4, l16 = lane & 15;
  const int q0 = qb * 64;

  bf16x8 qf[4];
  {
    const unsigned short* qp =
        Q + ((size_t)h * T_SEQ + q0 + wave * 16 + l16) * HD + quad * 8;
#pragma unroll
    for (int c2 = 0; c2 < 4; c2++) qf[c2] = *(const bf16x8*)(qp + c2 * 32);
  }

  f32x4 o_acc[8] = {};
  float mrow[4] = {-INFINITY, -INFINITY, -INFINITY, -INFINITY};
  float lrow[4] = {0.f, 0.f, 0.f, 0.f};
  const float l2e_s = 1.4426950408889634f * 0.08838834764831845f;
  const int nkt = (q0 + 64) >> 5;  // causal bound: key tiles 0..2qb+1

  const unsigned short* kb = K + (size_t)kvh * T_SEQ * HD;
  const unsigned short* vb = V + (size_t)kvh * T_SEQ * HD;

  for (int kt = 0; kt < nkt; kt++) {
    const int kbase = kt * 32;
    __syncthreads();  // prior iter's LDS reads done before restage
    // stage K tile (row-major, padded) and V tile (transposed, padded)
#pragma unroll
    for (int it = 0; it < 2; it++) {
      const int ch = tid + it * 256;  // 0..511 : key = ch/16, d0 = (ch%16)*8
      const int key = ch >> 4, d0 = (ch & 15) * 8;
      uint4 kraw = *(const uint4*)(kb + (size_t)(kbase + key) * HD + d0);
      *(uint4*)(lds_k + key * PK + d0) = kraw;
      uint4 vraw = *(const uint4*)(vb + (size_t)(kbase + key) * HD + d0);
      const unsigned short* e = (const unsigned short*)&vraw;
#pragma unroll
      for (int i = 0; i < 8; i++) lds_vt[(d0 + i) * PV + key] = e[i];
    }
    __syncthreads();

    // S = Q K^T  (two 16-key n-tiles, contract 128 dims = 4 MFMAs each)
    f32x4 s0 = {}, s1 = {};
#pragma unroll
    for (int c2 = 0; c2 < 4; c2++) {
      bf16x8 b0 = lds_frag(lds_k + l16 * PK + c2 * 32 + quad * 8);
      bf16x8 b1 = lds_frag(lds_k + (16 + l16) * PK + c2 * 32 + quad * 8);
      s0 = __builtin_amdgcn_mfma_f32_16x16x32_bf16(qf[c2], b0, s0, 0, 0, 0);
      s1 = __builtin_amdgcn_mfma_f32_16x16x32_bf16(qf[c2], b1, s1, 0, 0, 0);
    }

    // online softmax (C-layout: row = quad*4+r across regs, col = l16 across lanes)
    const int colg0 = kbase + l16, colg1 = kbase + 16 + l16;
#pragma unroll
    for (int r = 0; r < 4; r++) {
      const int row = q0 + wave * 16 + quad * 4 + r;
      float v0 = (colg0 <= row) ? s0[r] : -INFINITY;
      float v1 = (colg1 <= row) ? s1[r] : -INFINITY;
      float mx = fmaxf(v0, v1);
#pragma unroll
      for (int m = 1; m < 16; m <<= 1) mx = fmaxf(mx, __shfl_xor(mx, m, 16));
      const float mn = fmaxf(mrow[r], mx);
      const float alpha = exp2f((mrow[r] - mn) * l2e_s);
      const float p0 = exp2f((v0 - mn) * l2e_s);
      const float p1 = exp2f((v1 - mn) * l2e_s);
      float ps = p0 + p1;
#pragma unroll
      for (int m = 1; m < 16; m <<= 1) ps += __shfl_xor(ps, m, 16);
      lrow[r] = lrow[r] * alpha + ps;
      mrow[r] = mn;
#pragma unroll
      for (int dt = 0; dt < 8; dt++) o_acc[dt][r] *= alpha;
      lds_p[wave][(quad * 4 + r) * PV + l16] = f2bf(p0);
      lds_p[wave][(quad * 4 + r) * PV + 16 + l16] = f2bf(p1);
    }
    __syncthreads();  // P visible (and Vt staging already synced)

    // O += P V : A = P (16x32), B = Vt (32 x 128), 8 d-tiles
    const bf16x8 pa = lds_frag(lds_p[wave] + l16 * PV + quad * 8);
#pragma unroll
    for (int dt = 0; dt < 8; dt++) {
      bf16x8 vbf = lds_frag(lds_vt + (dt * 16 + l16) * PV + quad * 8);
      o_acc[dt] = __builtin_amdgcn_mfma_f32_16x16x32_bf16(pa, vbf, o_acc[dt], 0, 0, 0);
    }
  }

  // epilogue: O[token][h*128 + d] = o_acc / l
#pragma unroll
  for (int r = 0; r < 4; r++) {
    const float inv = 1.0f / lrow[r];
    const int row = q0 + wave * 16 + quad * 4 + r;
#pragma unroll
    for (int dt = 0; dt < 8; dt++)
      O[(size_t)row * QSIZE + h * HD + dt * 16 + l16] = f2bf(o_acc[dt][r] * inv);
  }
}

// ---------- launch ----------
extern "C" void kernel_launch(void* const* d_in, const int* in_sizes, int n_in,
                              void* d_out, int out_size, void* d_ws, size_t ws_size,
                              hipStream_t stream) {
  const float* hidden = (const float*)d_in[1];
  const float* w_qkv  = (const float*)d_in[2];
  const float* b_qkv  = (const float*)d_in[3];
  const float* q_norm = (const float*)d_in[4];
  const float* k_norm = (const float*)d_in[5];
  const float* w_o    = (const float*)d_in[6];
  float* out = (float*)d_out;

  char* ws = (char*)d_ws;
  unsigned short* hidden_bf = (unsigned short*)(ws + 0);          // 16 MB
  unsigned short* wqkv_bf   = (unsigned short*)(ws + 16777216);   // 48 MB
  unsigned short* wo_bf     = (unsigned short*)(ws + 67108864);   // 32 MB
  float*          qkv_f32   = (float*)(ws + 100663296);           // 48 MB
  unsigned short* q_bf      = (unsigned short*)(ws + 150994944);  // 16 MB
  unsigned short* k_bf      = (unsigned short*)(ws + 167772160);  // 4 MB
  unsigned short* v_bf      = (unsigned short*)(ws + 171966464);  // 4 MB
  unsigned short* attn_bf   = (unsigned short*)(ws + 176160768);  // 16 MB
  // total 192937984 bytes

  cvt_f32_bf16<<<(T_SEQ * HIDDEN / 4 + 255) / 256, 256, 0, stream>>>(
      hidden, hidden_bf, T_SEQ * HIDDEN / 4);
  cvt_f32_bf16<<<(QKV_N * HIDDEN / 4 + 255) / 256, 256, 0, stream>>>(
      w_qkv, wqkv_bf, QKV_N * HIDDEN / 4);
  cvt_f32_bf16<<<(HIDDEN * QSIZE / 4 + 255) / 256, 256, 0, stream>>>(
      w_o, wo_bf, HIDDEN * QSIZE / 4);

  gemm_bt<<<dim3(T_SEQ / 128, QKV_N / 128), 256, 0, stream>>>(
      hidden_bf, wqkv_bf, b_qkv, qkv_f32, T_SEQ, QKV_N, HIDDEN);

  norm_rope<<<dim3(48, T_SEQ), 128, 0, stream>>>(
      qkv_f32, q_norm, k_norm, q_bf, k_bf, v_bf);

  attn_fwd<<<dim3(NUM_HEADS, T_SEQ / 64), 256, 0, stream>>>(
      q_bf, k_bf, v_bf, attn_bf);

  gemm_bt<<<dim3(T_SEQ / 128, HIDDEN / 128), 256, 0, stream>>>(
      attn_bf, wo_bf, nullptr, out, T_SEQ, HIDDEN, QSIZE);
}

// Round 2
// 635.170 us; speedup vs baseline: 1.2484x; 1.2484x over previous
//
#include <hip/hip_runtime.h>
#include <stdint.h>

#define T_SEQ 2048
#define HIDDEN 4096
#define NUM_HEADS 32
#define NUM_KV 8
#define HD 128
#define QSIZE (NUM_HEADS * HD)       /* 4096 */
#define KVSIZE (NUM_KV * HD)         /* 1024 */
#define QKV_N (QSIZE + 2 * KVSIZE)   /* 6144 */

typedef __attribute__((ext_vector_type(8))) __bf16 bf16x8;
typedef __attribute__((ext_vector_type(4))) float f32x4;

// ---------- helpers ----------
static __device__ __forceinline__ unsigned short f2bf(float f) {
  union { float f; unsigned int u; } v; v.f = f;
  unsigned int u = v.u;
  return (unsigned short)((u + 0x7FFFu + ((u >> 16) & 1u)) >> 16);
}

static __device__ __forceinline__ void async16(const void* g, void* l) {
  __builtin_amdgcn_global_load_lds((__attribute__((address_space(1))) void*)g,
                                   (__attribute__((address_space(3))) void*)l,
                                   16, 0, 0);
}

static __device__ __forceinline__ bf16x8 lds_frag(const unsigned short* p) {
  return *(const bf16x8*)p;
}

// ---------- fp32 -> bf16 cast ----------
__global__ void cvt_f32_bf16(const float* __restrict__ src,
                             unsigned short* __restrict__ dst, int n4) {
  int i = blockIdx.x * 256 + threadIdx.x;
  if (i >= n4) return;
  float4 f = ((const float4*)src)[i];
  ushort4 o;
  o.x = f2bf(f.x); o.y = f2bf(f.y); o.z = f2bf(f.z); o.w = f2bf(f.w);
  ((ushort4*)dst)[i] = o;
}

// ---------- GEMM: C[M][N] = A[M][K] * Bt[N][K]^T (+bias) ----------
__global__ __launch_bounds__(256) void gemm_bt(
    const unsigned short* __restrict__ A,
    const unsigned short* __restrict__ Bt,
    const float* __restrict__ bias,
    float* __restrict__ C, int M, int N, int K) {
  __shared__ unsigned short lds_a[128 * 32];
  __shared__ unsigned short lds_b[128 * 32];
  const int tid = threadIdx.x;
  const int wave = tid >> 6, lane = tid & 63;
  const int quad = lane >> 4, l16 = lane & 15;
  const int row0 = blockIdx.x * 128, col0 = blockIdx.y * 128;
  const int wm = (wave >> 1) * 64, wn = (wave & 1) * 64;

  f32x4 acc[4][4] = {};

  const int e0 = wave * 1024 + lane * 8;
  const int e1 = e0 + 512;
  const unsigned short* Ab0 = A + (size_t)(row0 + (e0 >> 5)) * K + (e0 & 31);
  const unsigned short* Ab1 = A + (size_t)(row0 + (e1 >> 5)) * K + (e1 & 31);
  const unsigned short* Bb0 = Bt + (size_t)(col0 + (e0 >> 5)) * K + (e0 & 31);
  const unsigned short* Bb1 = Bt + (size_t)(col0 + (e1 >> 5)) * K + (e1 & 31);
  unsigned short* la0 = lds_a + wave * 1024;
  unsigned short* la1 = la0 + 512;
  unsigned short* lb0 = lds_b + wave * 1024;
  unsigned short* lb1 = lb0 + 512;

  for (int k0 = 0; k0 < K; k0 += 32) {
    __syncthreads();
    async16(Ab0 + k0, la0);
    async16(Ab1 + k0, la1);
    async16(Bb0 + k0, lb0);
    async16(Bb1 + k0, lb1);
    __syncthreads();
    bf16x8 af[4], bfr[4];
#pragma unroll
    for (int mt = 0; mt < 4; mt++)
      af[mt] = lds_frag(lds_a + (wm + mt * 16 + l16) * 32 + quad * 8);
#pragma unroll
    for (int nt = 0; nt < 4; nt++)
      bfr[nt] = lds_frag(lds_b + (wn + nt * 16 + l16) * 32 + quad * 8);
#pragma unroll
    for (int mt = 0; mt < 4; mt++)
#pragma unroll
      for (int nt = 0; nt < 4; nt++)
        acc[mt][nt] = __builtin_amdgcn_mfma_f32_16x16x32_bf16(
            af[mt], bfr[nt], acc[mt][nt], 0, 0, 0);
  }

#pragma unroll
  for (int mt = 0; mt < 4; mt++) {
#pragma unroll
    for (int nt = 0; nt < 4; nt++) {
      const int c = col0 + wn + nt * 16 + l16;
      const float bv = bias ? bias[c] : 0.0f;
      const int rbase = row0 + wm + mt * 16 + quad * 4;
#pragma unroll
      for (int r = 0; r < 4; r++)
        C[(size_t)(rbase + r) * N + c] = acc[mt][nt][r] + bv;
    }
  }
}

// ---------- RMSNorm + RoPE (q + k only), emit head-major bf16 ----------
// grid (40, 2048), block 128. slot 0..31 = q head, 32..39 = k head.
__global__ void norm_rope(const float* __restrict__ qkv,
                          const float* __restrict__ qw,
                          const float* __restrict__ kw,
                          unsigned short* __restrict__ q,
                          unsigned short* __restrict__ k) {
  const int slot = blockIdx.x;
  const int t = blockIdx.y;
  const int d = threadIdx.x;
  const float* src = (slot < 32)
      ? qkv + (size_t)t * QKV_N + slot * HD
      : qkv + (size_t)t * QKV_N + QSIZE + (slot - 32) * HD;
  float x = src[d];
  __shared__ float red[2];
  __shared__ float ylds[HD];
  float ss = x * x;
#pragma unroll
  for (int m = 32; m >= 1; m >>= 1) ss += __shfl_xor(ss, m, 64);
  if ((d & 63) == 0) red[d >> 6] = ss;
  __syncthreads();
  const float rn = rsqrtf((red[0] + red[1]) * (1.0f / 128.0f) + 1e-5f);
  const float* w = (slot < 32) ? qw : kw;
  const float y = x * rn * w[d];
  ylds[d] = y;
  __syncthreads();
  float out;
  if (d < 64) {
    const int j = d & 31;
    const float inv = exp2f(-(float)j * (13.28771237954945f / 32.0f));
    const float ang = (float)t * inv;
    float s, c;
    sincosf(ang, &s, &c);
    const float x1 = ylds[j], x2 = ylds[j + 32];
    out = (d < 32) ? (x1 * c - x2 * s) : (x2 * c + x1 * s);
  } else {
    out = y;
  }
  if (slot < 32) q[((size_t)slot * T_SEQ + t) * HD + d] = f2bf(out);
  else           k[((size_t)(slot - 32) * T_SEQ + t) * HD + d] = f2bf(out);
}

// ---------- V transpose: qkv_f32 v-slice -> Vt[kvh][d][T] bf16 ----------
// grid (8, 32) = (kvh, 64-token tile), 256 threads.
__global__ __launch_bounds__(256) void transpose_v(
    const float* __restrict__ qkv, unsigned short* __restrict__ vt) {
  __shared__ unsigned short tile[64 * 136];  // [t][d], stride 136
  const int kvh = blockIdx.x, tt = blockIdx.y;
  const int tid = threadIdx.x;
  {
    const int t_r = tid >> 2, d0 = (tid & 3) * 32;
    const float* src = qkv + (size_t)(tt * 64 + t_r) * QKV_N +
                       (QSIZE + KVSIZE) + kvh * HD + d0;
#pragma unroll
    for (int i = 0; i < 8; i++) {
      float4 f = ((const float4*)src)[i];
      unsigned short* dptr = tile + t_r * 136 + d0 + i * 4;
      dptr[0] = f2bf(f.x); dptr[1] = f2bf(f.y);
      dptr[2] = f2bf(f.z); dptr[3] = f2bf(f.w);
    }
  }
  __syncthreads();
  {
    const int d_r = tid >> 1, t0 = (tid & 1) * 32;
    unsigned short buf[32];
#pragma unroll
    for (int i = 0; i < 32; i++) buf[i] = tile[(t0 + i) * 136 + d_r];
    uint4* dst = (uint4*)(vt + ((size_t)kvh * HD + d_r) * T_SEQ + tt * 64 + t0);
#pragma unroll
    for (int i = 0; i < 4; i++) dst[i] = ((uint4*)buf)[i];
  }
}

// ---------- flash attention (causal, GQA 4:1) ----------
// 512 blocks (LPT order: big qb first), 256 threads.
// Block = 128 q-rows; wave owns 32 rows (2 m-frags). Bc = 64 keys/tile.
#define BC 64
#define KCH 528  /* K LDS chunk stride: 4 rows x 128 + 16 pad */
#define VCH 544  /* Vt LDS chunk stride: 8 rows x 64 + 32 pad */
#define PST 72   /* P row stride */
__global__ __launch_bounds__(256) void attn_fwd(
    const unsigned short* __restrict__ Q,   // [32][2048][128]
    const unsigned short* __restrict__ K,   // [8][2048][128]
    const unsigned short* __restrict__ Vt,  // [8][128][2048]
    unsigned short* __restrict__ O) {       // [2048][4096]
  __shared__ unsigned short lds_k[16 * KCH];
  __shared__ unsigned short lds_v[16 * VCH];
  __shared__ unsigned short lds_p[4 * 32 * PST];

  const int bx = blockIdx.x;
  const int qb = 15 - (bx >> 5);  // largest-work blocks dispatch first
  const int h = bx & 31;
  const int kvh = h >> 2;
  const int tid = threadIdx.x, wave = tid >> 6, lane = tid & 63;
  const int quad = lane >> 4, l16 = lane & 15;
  const int q0 = qb * 128;
  const int mrow0 = q0 + wave * 32;

  // Q fragments (held in registers for the whole block)
  bf16x8 qf[2][4];
#pragma unroll
  for (int m = 0; m < 2; m++) {
    const unsigned short* qp =
        Q + ((size_t)h * T_SEQ + mrow0 + m * 16 + l16) * HD + quad * 8;
#pragma unroll
    for (int c2 = 0; c2 < 4; c2++) qf[m][c2] = *(const bf16x8*)(qp + c2 * 32);
  }

  f32x4 o_acc[2][8] = {};
  float mrow[2][4], lrow[2][4];
#pragma unroll
  for (int m = 0; m < 2; m++)
#pragma unroll
    for (int r = 0; r < 4; r++) { mrow[m][r] = -INFINITY; lrow[m][r] = 0.f; }

  const float l2e_s = 1.4426950408889634f * 0.08838834764831845f;
  const unsigned short* kb = K + (size_t)kvh * T_SEQ * HD;
  const unsigned short* vtb = Vt + (size_t)kvh * HD * T_SEQ;
  unsigned short* pbase = lds_p + wave * 32 * PST;

  const int nkt = 2 * (qb + 1);
  for (int kt = 0; kt < nkt; kt++) {
    const int kbase = kt * BC;
    __syncthreads();  // all waves done reading prior K/V tiles
#pragma unroll
    for (int cc = 0; cc < 4; cc++) {
      const int c = wave + cc * 4;  // chunk id 0..15
      async16(kb + (size_t)(kbase + c * 4 + (lane >> 4)) * HD + (lane & 15) * 8,
              lds_k + c * KCH + lane * 8);
      async16(vtb + (size_t)(c * 8 + (lane >> 3)) * T_SEQ + kbase + (lane & 7) * 8,
              lds_v + c * VCH + lane * 8);
    }
    __syncthreads();  // staging visible

    // ---- S = Q K^T (2 m-frags x 4 n-frags, contract 128) ----
    f32x4 s[2][4] = {};
#pragma unroll
    for (int c2 = 0; c2 < 4; c2++) {
#pragma unroll
      for (int nt = 0; nt < 4; nt++) {
        bf16x8 kf = lds_frag(lds_k + (nt * 4 + (l16 >> 2)) * KCH +
                             (l16 & 3) * 128 + c2 * 32 + quad * 8);
        s[0][nt] = __builtin_amdgcn_mfma_f32_16x16x32_bf16(qf[0][c2], kf, s[0][nt], 0, 0, 0);
        s[1][nt] = __builtin_amdgcn_mfma_f32_16x16x32_bf16(qf[1][c2], kf, s[1][nt], 0, 0, 0);
      }
    }

    // ---- online softmax (C-layout: row = quad*4+r, col = nt*16+l16) ----
    const bool domask = (kbase + 63 > mrow0);
#pragma unroll
    for (int m = 0; m < 2; m++) {
#pragma unroll
      for (int r = 0; r < 4; r++) {
        const int row = mrow0 + m * 16 + quad * 4 + r;
        float vv[4];
#pragma unroll
        for (int nt = 0; nt < 4; nt++) {
          float x = s[m][nt][r];
          if (domask && (kbase + nt * 16 + l16 > row)) x = -INFINITY;
          vv[nt] = x;
        }
        float mx = fmaxf(fmaxf(vv[0], vv[1]), fmaxf(vv[2], vv[3]));
#pragma unroll
        for (int msk = 1; msk < 16; msk <<= 1) mx = fmaxf(mx, __shfl_xor(mx, msk, 16));
        const float mn = fmaxf(mrow[m][r], mx);
        const float alpha = exp2f((mrow[m][r] - mn) * l2e_s);
        float p[4], ps = 0.f;
#pragma unroll
        for (int nt = 0; nt < 4; nt++) { p[nt] = exp2f((vv[nt] - mn) * l2e_s); ps += p[nt]; }
#pragma unroll
        for (int msk = 1; msk < 16; msk <<= 1) ps += __shfl_xor(ps, msk, 16);
        lrow[m][r] = lrow[m][r] * alpha + ps;
        mrow[m][r] = mn;
#pragma unroll
        for (int dt = 0; dt < 8; dt++) o_acc[m][dt][r] *= alpha;
        unsigned short* pw = pbase + (m * 16 + quad * 4 + r) * PST + l16;
#pragma unroll
        for (int nt = 0; nt < 4; nt++) pw[nt * 16] = f2bf(p[nt]);
      }
    }
    // P is per-wave: no barrier needed (in-wave lgkmcnt ordering)

    // ---- O += P V (2 k-steps over 64 keys, 8 d-frags) ----
#pragma unroll
    for (int ks = 0; ks < 2; ks++) {
      bf16x8 pa0 = lds_frag(pbase + l16 * PST + ks * 32 + quad * 8);
      bf16x8 pa1 = lds_frag(pbase + (16 + l16) * PST + ks * 32 + quad * 8);
#pragma unroll
      for (int dt = 0; dt < 8; dt++) {
        bf16x8 vf = lds_frag(lds_v + (dt * 2 + (l16 >> 3)) * VCH +
                             (l16 & 7) * 64 + ks * 32 + quad * 8);
        o_acc[0][dt] = __builtin_amdgcn_mfma_f32_16x16x32_bf16(pa0, vf, o_acc[0][dt], 0, 0, 0);
        o_acc[1][dt] = __builtin_amdgcn_mfma_f32_16x16x32_bf16(pa1, vf, o_acc[1][dt], 0, 0, 0);
      }
    }
  }

  // ---- epilogue ----
#pragma unroll
  for (int m = 0; m < 2; m++) {
#pragma unroll
    for (int r = 0; r < 4; r++) {
      const float inv = 1.0f / lrow[m][r];
      const int row = mrow0 + m * 16 + quad * 4 + r;
#pragma unroll
      for (int dt = 0; dt < 8; dt++)
        O[(size_t)row * QSIZE + h * HD + dt * 16 + l16] =
            f2bf(o_acc[m][dt][r] * inv);
    }
  }
}

// ---------- launch ----------
extern "C" void kernel_launch(void* const* d_in, const int* in_sizes, int n_in,
                              void* d_out, int out_size, void* d_ws, size_t ws_size,
                              hipStream_t stream) {
  const float* hidden = (const float*)d_in[1];
  const float* w_qkv  = (const float*)d_in[2];
  const float* b_qkv  = (const float*)d_in[3];
  const float* q_norm = (const float*)d_in[4];
  const float* k_norm = (const float*)d_in[5];
  const float* w_o    = (const float*)d_in[6];
  float* out = (float*)d_out;

  char* ws = (char*)d_ws;
  unsigned short* hidden_bf = (unsigned short*)(ws + 0);          // 16 MB
  unsigned short* wqkv_bf   = (unsigned short*)(ws + 16777216);   // 48 MB
  unsigned short* wo_bf     = (unsigned short*)(ws + 67108864);   // 32 MB
  float*          qkv_f32   = (float*)(ws + 100663296);           // 48 MB
  unsigned short* q_bf      = (unsigned short*)(ws + 150994944);  // 16 MB
  unsigned short* k_bf      = (unsigned short*)(ws + 167772160);  // 4 MB
  unsigned short* vt_bf     = (unsigned short*)(ws + 171966464);  // 4 MB
  unsigned short* attn_bf   = (unsigned short*)(ws + 176160768);  // 16 MB

  cvt_f32_bf16<<<(T_SEQ * HIDDEN / 4 + 255) / 256, 256, 0, stream>>>(
      hidden, hidden_bf, T_SEQ * HIDDEN / 4);
  cvt_f32_bf16<<<(QKV_N * HIDDEN / 4 + 255) / 256, 256, 0, stream>>>(
      w_qkv, wqkv_bf, QKV_N * HIDDEN / 4);
  cvt_f32_bf16<<<(HIDDEN * QSIZE / 4 + 255) / 256, 256, 0, stream>>>(
      w_o, wo_bf, HIDDEN * QSIZE / 4);

  gemm_bt<<<dim3(T_SEQ / 128, QKV_N / 128), 256, 0, stream>>>(
      hidden_bf, wqkv_bf, b_qkv, qkv_f32, T_SEQ, QKV_N, HIDDEN);

  norm_rope<<<dim3(40, T_SEQ), 128, 0, stream>>>(
      qkv_f32, q_norm, k_norm, q_bf, k_bf);

  transpose_v<<<dim3(8, T_SEQ / 64), 256, 0, stream>>>(qkv_f32, vt_bf);

  attn_fwd<<<dim3(512), 256, 0, stream>>>(q_bf, k_bf, vt_bf, attn_bf);

  gemm_bt<<<dim3(T_SEQ / 128, HIDDEN / 128), 256, 0, stream>>>(
      attn_bf, wo_bf, nullptr, out, T_SEQ, HIDDEN, QSIZE);
}